// Round 7
// baseline (335.219 us; speedup 1.0000x reference)
//
#include <hip/hip_runtime.h>
#include <hip/hip_bf16.h>

typedef __attribute__((ext_vector_type(8))) short short8;
typedef __attribute__((ext_vector_type(4))) float floatx4;

#define NN 4096

static __device__ __forceinline__ unsigned f2bf_rne(float x) {
    union { float f; unsigned u; } v; v.f = x;
    unsigned r = v.u + 0x7fffu + ((v.u >> 16) & 1u);
    return r >> 16;
}
static __device__ __forceinline__ float bf2f(unsigned hi) {
    union { unsigned u; float f; } v; v.u = hi << 16; return v.f;
}

// ---- prep (fused wc): per-block computes Wc=W1@W2, w1·alpha; then
// G = X@Wc (bf16 hi/lo MFMA) -> Gt bf16 [b*64+c][4096]; lv/rv fp32.  (R6-proven)
__global__ __launch_bounds__(256, 4)
void prep_kernel(const float* __restrict__ X,
                 const float* __restrict__ W1,
                 const float* __restrict__ W2,
                 const float* __restrict__ alpha,
                 unsigned short* __restrict__ Gt,
                 float* __restrict__ lv,
                 float* __restrict__ rv) {
    __shared__ __align__(16) char sm[53248];
    float* W1s  = (float*)sm;                 // [64][68]
    float* W2s  = (float*)(sm + 17408);       // [64][68]
    float* Wcst = (float*)(sm + 34816);       // Wc^T: [n][k] stride 68
    float* w1s  = (float*)(sm + 52224);       // [128]
    float* als  = (float*)(sm + 52736);       // [128]
    float* GsT  = (float*)sm;                 // epilogue reuse: [64][68]

    const int t = threadIdx.x;
    const int row0 = blockIdx.x * 64;         // flat b*N + n
    const int b = row0 >> 12, n0 = row0 & (NN - 1);
    const int w = t >> 6, lane = t & 63;
    const int m = lane & 15, q = lane >> 4;

    const int row = row0 + w * 16 + m;
    const float* xp = X + (size_t)row * 64;
    float4 x0 = *(const float4*)(xp + q * 8);
    float4 x1 = *(const float4*)(xp + q * 8 + 4);
    float4 x2 = *(const float4*)(xp + 32 + q * 8);
    float4 x3 = *(const float4*)(xp + 32 + q * 8 + 4);

    #pragma unroll
    for (int s = 0; s < 4; ++s) {
        int idx = s * 1024 + t * 4;
        int r = idx >> 6, cc = idx & 63;
        *(float4*)&W1s[r * 68 + cc] = *(const float4*)(W1 + idx);
        *(float4*)&W2s[r * 68 + cc] = *(const float4*)(W2 + idx);
    }
    if (t < 128) als[t] = alpha[t];
    __syncthreads();

    {   // Wc^T: thread (k = t>>2, nq = t&3)
        const int k = t >> 2, nq = t & 3;
        float acc[16];
        #pragma unroll
        for (int i = 0; i < 16; ++i) acc[i] = 0.f;
        for (int mm = 0; mm < 64; ++mm) {
            float w1v = W1s[k * 68 + mm];
            #pragma unroll
            for (int i = 0; i < 16; ++i)
                acc[i] += w1v * W2s[mm * 68 + nq * 16 + i];
        }
        #pragma unroll
        for (int i = 0; i < 16; ++i)
            Wcst[(nq * 16 + i) * 68 + k] = acc[i];
    }
    if (t < 64) {
        float sl = 0.f, sr = 0.f;
        for (int cc2 = 0; cc2 < 64; ++cc2) {
            float wv = W1s[t * 68 + cc2];
            sl += wv * als[cc2];
            sr += wv * als[64 + cc2];
        }
        w1s[t] = sl; w1s[64 + t] = sr;
    }
    __syncthreads();

    const float xs[16] = {x0.x,x0.y,x0.z,x0.w, x1.x,x1.y,x1.z,x1.w,
                          x2.x,x2.y,x2.z,x2.w, x3.x,x3.y,x3.z,x3.w};

    float pl = 0.f, pr = 0.f;
    #pragma unroll
    for (int ks = 0; ks < 2; ++ks)
        #pragma unroll
        for (int j = 0; j < 8; ++j) {
            int k = ks * 32 + q * 8 + j;
            float xv = xs[ks * 8 + j];
            pl += xv * w1s[k];
            pr += xv * w1s[64 + k];
        }
    pl += __shfl_xor(pl, 16, 64); pl += __shfl_xor(pl, 32, 64);
    pr += __shfl_xor(pr, 16, 64); pr += __shfl_xor(pr, 32, 64);
    if (q == 0) { lv[row] = pl; rv[row] = pr; }

    short8 ah[2], al[2];
    #pragma unroll
    for (int ks = 0; ks < 2; ++ks)
        #pragma unroll
        for (int j = 0; j < 8; ++j) {
            float f = xs[ks * 8 + j];
            unsigned hb = f2bf_rne(f);
            float res = f - bf2f(hb);
            ah[ks][j] = (short)hb;
            al[ks][j] = (short)f2bf_rne(res);
        }

    short8 bfr[4][2];
    #pragma unroll
    for (int nt = 0; nt < 4; ++nt)
        #pragma unroll
        for (int ks = 0; ks < 2; ++ks) {
            const float* wp = &Wcst[(nt * 16 + m) * 68 + ks * 32 + q * 8];
            float4 w0 = *(const float4*)wp;
            float4 w1 = *(const float4*)(wp + 4);
            short8 bf;
            bf[0] = (short)f2bf_rne(w0.x); bf[1] = (short)f2bf_rne(w0.y);
            bf[2] = (short)f2bf_rne(w0.z); bf[3] = (short)f2bf_rne(w0.w);
            bf[4] = (short)f2bf_rne(w1.x); bf[5] = (short)f2bf_rne(w1.y);
            bf[6] = (short)f2bf_rne(w1.z); bf[7] = (short)f2bf_rne(w1.w);
            bfr[nt][ks] = bf;
        }

    floatx4 acc[4] = {{0,0,0,0},{0,0,0,0},{0,0,0,0},{0,0,0,0}};
    #pragma unroll
    for (int ks = 0; ks < 2; ++ks)
        #pragma unroll
        for (int nt = 0; nt < 4; ++nt) {
            acc[nt] = __builtin_amdgcn_mfma_f32_16x16x32_bf16(ah[ks], bfr[nt][ks], acc[nt], 0, 0, 0);
            acc[nt] = __builtin_amdgcn_mfma_f32_16x16x32_bf16(al[ks], bfr[nt][ks], acc[nt], 0, 0, 0);
        }

    __syncthreads();
    #pragma unroll
    for (int nt = 0; nt < 4; ++nt)
        #pragma unroll
        for (int rg = 0; rg < 4; ++rg)
            GsT[(nt * 16 + m) * 68 + w * 16 + q * 4 + rg] = acc[nt][rg];
    __syncthreads();
    unsigned* Gu = (unsigned*)Gt;
    #pragma unroll
    for (int it2 = 0; it2 < 8; ++it2) {
        int c2 = (t >> 5) + it2 * 8;
        int np = t & 31;
        unsigned lo = f2bf_rne(GsT[c2 * 68 + 2 * np]);
        unsigned hi = f2bf_rne(GsT[c2 * 68 + 2 * np + 1]);
        Gu[(((((size_t)(b * 64 + c2)) << 12) + n0) >> 1) + np] = lo | (hi << 16);
    }
}

// ---- attn v7: block = (i-tile 64, b), 1024 thr = 16 independent waves
// (wsub: 32 i-rows, jq: 512-j slice). ZERO barriers / LDS in K-loop: each wave
// builds its E-fragments in registers (lane m -> row), reads G-frags direct
// from L2-resident Gt, accumulates num (8 MFMA) + den (2 ones-MFMA) per chunk.
// Diag term corrected in fp32 epilogue (removed from hot loop). Cross-jq
// reduction via LDS in 4 passes, fused divide + direct out store.
__global__ __launch_bounds__(1024, 4)
void attn_kernel(const float* __restrict__ A,
                 const unsigned short* __restrict__ Gt,
                 const float* __restrict__ lv,
                 const float* __restrict__ rv,
                 float* __restrict__ out) {
    __shared__ __align__(16) float red[2][64][68];
    const int bx = blockIdx.x;
    const int i0 = (bx & 63) * 64;
    const int b  = bx >> 6;
    const int t = threadIdx.x;
    const int wave = t >> 6, lane = t & 63;
    const int wsub = wave & 1, jq = wave >> 1;
    const int m = lane & 15, q = lane >> 4;

    const int r0g = i0 + wsub * 32 + m;                      // row set0 (global)
    const float li0 = lv[b * NN + r0g] * 1.44269504f;        // fold log2e
    const float li1 = lv[b * NN + r0g + 16] * 1.44269504f;

    const float* a0p = A + (size_t)r0g * NN + jq * 512 + q * 8;
    const float* a1p = a0p + (size_t)16 * NN;
    const unsigned short* gp = Gt + (((size_t)(b * 64 + m)) << 12) + jq * 512 + q * 8;
    const float* rvp = rv + b * NN + jq * 512 + q * 8;

    floatx4 acc00 = {0,0,0,0}, acc01 = {0,0,0,0}, acc02 = {0,0,0,0}, acc03 = {0,0,0,0};
    floatx4 acc10 = {0,0,0,0}, acc11 = {0,0,0,0}, acc12 = {0,0,0,0}, acc13 = {0,0,0,0};
    floatx4 accd0 = {0,0,0,0}, accd1 = {0,0,0,0};
    short8 ones;
    #pragma unroll
    for (int e = 0; e < 8; ++e) ones[e] = (short)0x3F80;     // bf16 1.0

    auto genE = [&](float li, float4 a0, float4 a1, const float* rr) -> short8 {
        const float aa[8] = {a0.x, a0.y, a0.z, a0.w, a1.x, a1.y, a1.z, a1.w};
        unsigned ew[4];
        #pragma unroll
        for (int e2 = 0; e2 < 4; ++e2) {
            float s0 = li * rr[2 * e2], s1 = li * rr[2 * e2 + 1];
            s0 = fmaxf(s0, 0.01f * s0);                      // leaky_relu slope .01
            s1 = fmaxf(s1, 0.01f * s1);
            float e0 = exp2f(s0) * aa[2 * e2];
            float e1 = exp2f(s1) * aa[2 * e2 + 1];
            ew[e2] = __builtin_amdgcn_perm(__float_as_uint(e1) + 0x8000u,
                                           __float_as_uint(e0) + 0x8000u, 0x07060302u);
        }
        union { uint4 u; short8 s; } pk;
        pk.u.x = ew[0]; pk.u.y = ew[1]; pk.u.z = ew[2]; pk.u.w = ew[3];
        return pk.s;
    };

    auto step = [&](int o, float4 x0, float4 x1, float4 y0, float4 y1,
                    uint4 gu0, uint4 gu1, uint4 gu2, uint4 gu3) {
        float4 rv0 = *(const float4*)(rvp + o);
        float4 rv1 = *(const float4*)(rvp + o + 4);
        const float rr[8] = {rv0.x, rv0.y, rv0.z, rv0.w, rv1.x, rv1.y, rv1.z, rv1.w};
        short8 e0 = genE(li0, x0, x1, rr);
        short8 e1 = genE(li1, y0, y1, rr);
        union { uint4 u; short8 s; } g0, g1, g2, g3;
        g0.u = gu0; g1.u = gu1; g2.u = gu2; g3.u = gu3;
        acc00 = __builtin_amdgcn_mfma_f32_16x16x32_bf16(e0, g0.s, acc00, 0, 0, 0);
        acc01 = __builtin_amdgcn_mfma_f32_16x16x32_bf16(e0, g1.s, acc01, 0, 0, 0);
        acc02 = __builtin_amdgcn_mfma_f32_16x16x32_bf16(e0, g2.s, acc02, 0, 0, 0);
        acc03 = __builtin_amdgcn_mfma_f32_16x16x32_bf16(e0, g3.s, acc03, 0, 0, 0);
        accd0 = __builtin_amdgcn_mfma_f32_16x16x32_bf16(e0, ones, accd0, 0, 0, 0);
        acc10 = __builtin_amdgcn_mfma_f32_16x16x32_bf16(e1, g0.s, acc10, 0, 0, 0);
        acc11 = __builtin_amdgcn_mfma_f32_16x16x32_bf16(e1, g1.s, acc11, 0, 0, 0);
        acc12 = __builtin_amdgcn_mfma_f32_16x16x32_bf16(e1, g2.s, acc12, 0, 0, 0);
        acc13 = __builtin_amdgcn_mfma_f32_16x16x32_bf16(e1, g3.s, acc13, 0, 0, 0);
        accd1 = __builtin_amdgcn_mfma_f32_16x16x32_bf16(e1, ones, accd1, 0, 0, 0);
    };

    #define LDCHUNK(o, X0, X1, Y0, Y1, G0, G1, G2, G3)                      \
        X0 = *(const float4*)(a0p + (o));                                   \
        X1 = *(const float4*)(a0p + (o) + 4);                               \
        Y0 = *(const float4*)(a1p + (o));                                   \
        Y1 = *(const float4*)(a1p + (o) + 4);                               \
        G0 = *(const uint4*)(gp + (o));                                     \
        G1 = *(const uint4*)(gp + (o) + (16 << 12));                        \
        G2 = *(const uint4*)(gp + (o) + (32 << 12));                        \
        G3 = *(const uint4*)(gp + (o) + (48 << 12));

    float4 Ax0, Ax1, Ay0, Ay1; uint4 Ag0, Ag1, Ag2, Ag3;
    float4 Bx0, Bx1, By0, By1; uint4 Bg0, Bg1, Bg2, Bg3;
    LDCHUNK(0,  Ax0, Ax1, Ay0, Ay1, Ag0, Ag1, Ag2, Ag3);
    LDCHUNK(32, Bx0, Bx1, By0, By1, Bg0, Bg1, Bg2, Bg3);

    for (int jj = 0; jj < 512; jj += 64) {
        float4 cx0 = Ax0, cx1 = Ax1, cy0 = Ay0, cy1 = Ay1;
        uint4 cg0 = Ag0, cg1 = Ag1, cg2 = Ag2, cg3 = Ag3;
        const int jn0 = (jj + 64 < 512) ? jj + 64 : jj;      // clamp tail (unused re-read)
        LDCHUNK(jn0, Ax0, Ax1, Ay0, Ay1, Ag0, Ag1, Ag2, Ag3);
        step(jj, cx0, cx1, cy0, cy1, cg0, cg1, cg2, cg3);

        float4 dx0 = Bx0, dx1 = Bx1, dy0 = By0, dy1 = By1;
        uint4 dg0 = Bg0, dg1 = Bg1, dg2 = Bg2, dg3 = Bg3;
        const int jn1 = (jj + 96 < 512) ? jj + 96 : jj + 32;
        LDCHUNK(jn1, Bx0, Bx1, By0, By1, Bg0, Bg1, Bg2, Bg3);
        step(jj + 32, dx0, dx1, dy0, dy1, dg0, dg1, dg2, dg3);
    }
    #undef LDCHUNK

    // ---- epilogue: 4 passes x 2 jq-groups through LDS; accumulate in regs ----
    const int il = t >> 4, c4 = t & 15;
    float4 osum = {0.f, 0.f, 0.f, 0.f};
    float dsum = 0.f;
    #pragma unroll
    for (int p = 0; p < 4; ++p) {
        if ((jq >> 1) == p) {
            float (*rp)[68] = red[jq & 1];
            #pragma unroll
            for (int rg = 0; rg < 4; ++rg) {
                const int r0l = wsub * 32 + q * 4 + rg;
                rp[r0l][m]      = acc00[rg];
                rp[r0l][16 + m] = acc01[rg];
                rp[r0l][32 + m] = acc02[rg];
                rp[r0l][48 + m] = acc03[rg];
                rp[r0l + 16][m]      = acc10[rg];
                rp[r0l + 16][16 + m] = acc11[rg];
                rp[r0l + 16][32 + m] = acc12[rg];
                rp[r0l + 16][48 + m] = acc13[rg];
                if (m == 0) {
                    rp[r0l][64]      = accd0[rg];
                    rp[r0l + 16][64] = accd1[rg];
                }
            }
        }
        __syncthreads();
        {
            float4 v0 = *(const float4*)&red[0][il][c4 * 4];
            float4 v1 = *(const float4*)&red[1][il][c4 * 4];
            osum.x += v0.x + v1.x; osum.y += v0.y + v1.y;
            osum.z += v0.z + v1.z; osum.w += v0.w + v1.w;
            dsum += red[0][il][64] + red[1][il][64];
        }
        __syncthreads();
    }

    // ---- diag correction (fp32): replace a_ii*e_ii by 1*e_ii ----
    const int gi = i0 + il;
    {
        float lir = lv[b * NN + gi] * 1.44269504f;
        float rvi = rv[b * NN + gi];
        float s = lir * rvi;
        s = fmaxf(s, 0.01f * s);
        float eii = exp2f(s);
        float ad = A[(size_t)gi * NN + gi];
        float dc = (1.0f - ad) * eii;
        dsum += dc;
        osum.x += dc * bf2f(Gt[(((size_t)(b * 64 + c4 * 4 + 0)) << 12) + gi]);
        osum.y += dc * bf2f(Gt[(((size_t)(b * 64 + c4 * 4 + 1)) << 12) + gi]);
        osum.z += dc * bf2f(Gt[(((size_t)(b * 64 + c4 * 4 + 2)) << 12) + gi]);
        osum.w += dc * bf2f(Gt[(((size_t)(b * 64 + c4 * 4 + 3)) << 12) + gi]);
    }

    const float rinv = 1.0f / dsum;
    float4 o;
    o.x = osum.x * rinv; o.y = osum.y * rinv;
    o.z = osum.z * rinv; o.w = osum.w * rinv;
    *(float4*)(out + (((size_t)(b * NN + gi)) << 6) + c4 * 4) = o;
}

extern "C" void kernel_launch(void* const* d_in, const int* in_sizes, int n_in,
                              void* d_out, int out_size, void* d_ws, size_t ws_size,
                              hipStream_t stream) {
    const float* X     = (const float*)d_in[0];
    const float* A     = (const float*)d_in[1];
    const float* W1    = (const float*)d_in[2];
    const float* W2    = (const float*)d_in[3];
    const float* alpha = (const float*)d_in[4];
    float* out = (float*)d_out;

    char* ws = (char*)d_ws;
    unsigned short* Gt = (unsigned short*)(ws);            // 2 MiB
    float* lvp = (float*)(ws + 2097152);                   // 64 KiB
    float* rvp = (float*)(ws + 2097152 + 65536);           // 64 KiB

    prep_kernel<<<256, 256, 0, stream>>>(X, W1, W2, alpha, Gt, lvp, rvp);
    attn_kernel<<<256, 1024, 0, stream>>>(A, Gt, lvp, rvp, out);
}

// Round 8
// 235.431 us; speedup vs baseline: 1.4239x; 1.4239x over previous
//
#include <hip/hip_runtime.h>
#include <hip/hip_bf16.h>

typedef __attribute__((ext_vector_type(8))) short short8;
typedef __attribute__((ext_vector_type(4))) float floatx4;

#define NN 4096

static __device__ __forceinline__ unsigned f2bf_rne(float x) {
    union { float f; unsigned u; } v; v.f = x;
    unsigned r = v.u + 0x7fffu + ((v.u >> 16) & 1u);
    return r >> 16;
}
static __device__ __forceinline__ float bf2f(unsigned hi) {
    union { unsigned u; float f; } v; v.u = hi << 16; return v.f;
}

// ---- prep (fused wc): per-block computes Wc=W1@W2, w1·alpha; then
// G = X@Wc (bf16 hi/lo MFMA) -> Gt bf16 [b*64+c][4096]; lv/rv fp32.  (R6-proven)
__global__ __launch_bounds__(256, 4)
void prep_kernel(const float* __restrict__ X,
                 const float* __restrict__ W1,
                 const float* __restrict__ W2,
                 const float* __restrict__ alpha,
                 unsigned short* __restrict__ Gt,
                 float* __restrict__ lv,
                 float* __restrict__ rv) {
    __shared__ __align__(16) char sm[53248];
    float* W1s  = (float*)sm;                 // [64][68]
    float* W2s  = (float*)(sm + 17408);       // [64][68]
    float* Wcst = (float*)(sm + 34816);       // Wc^T: [n][k] stride 68
    float* w1s  = (float*)(sm + 52224);       // [128]
    float* als  = (float*)(sm + 52736);       // [128]
    float* GsT  = (float*)sm;                 // epilogue reuse: [64][68]

    const int t = threadIdx.x;
    const int row0 = blockIdx.x * 64;         // flat b*N + n
    const int b = row0 >> 12, n0 = row0 & (NN - 1);
    const int w = t >> 6, lane = t & 63;
    const int m = lane & 15, q = lane >> 4;

    const int row = row0 + w * 16 + m;
    const float* xp = X + (size_t)row * 64;
    float4 x0 = *(const float4*)(xp + q * 8);
    float4 x1 = *(const float4*)(xp + q * 8 + 4);
    float4 x2 = *(const float4*)(xp + 32 + q * 8);
    float4 x3 = *(const float4*)(xp + 32 + q * 8 + 4);

    #pragma unroll
    for (int s = 0; s < 4; ++s) {
        int idx = s * 1024 + t * 4;
        int r = idx >> 6, cc = idx & 63;
        *(float4*)&W1s[r * 68 + cc] = *(const float4*)(W1 + idx);
        *(float4*)&W2s[r * 68 + cc] = *(const float4*)(W2 + idx);
    }
    if (t < 128) als[t] = alpha[t];
    __syncthreads();

    {   // Wc^T: thread (k = t>>2, nq = t&3)
        const int k = t >> 2, nq = t & 3;
        float acc[16];
        #pragma unroll
        for (int i = 0; i < 16; ++i) acc[i] = 0.f;
        for (int mm = 0; mm < 64; ++mm) {
            float w1v = W1s[k * 68 + mm];
            #pragma unroll
            for (int i = 0; i < 16; ++i)
                acc[i] += w1v * W2s[mm * 68 + nq * 16 + i];
        }
        #pragma unroll
        for (int i = 0; i < 16; ++i)
            Wcst[(nq * 16 + i) * 68 + k] = acc[i];
    }
    if (t < 64) {
        float sl = 0.f, sr = 0.f;
        for (int cc2 = 0; cc2 < 64; ++cc2) {
            float wv = W1s[t * 68 + cc2];
            sl += wv * als[cc2];
            sr += wv * als[64 + cc2];
        }
        w1s[t] = sl; w1s[64 + t] = sr;
    }
    __syncthreads();

    const float xs[16] = {x0.x,x0.y,x0.z,x0.w, x1.x,x1.y,x1.z,x1.w,
                          x2.x,x2.y,x2.z,x2.w, x3.x,x3.y,x3.z,x3.w};

    float pl = 0.f, pr = 0.f;
    #pragma unroll
    for (int ks = 0; ks < 2; ++ks)
        #pragma unroll
        for (int j = 0; j < 8; ++j) {
            int k = ks * 32 + q * 8 + j;
            float xv = xs[ks * 8 + j];
            pl += xv * w1s[k];
            pr += xv * w1s[64 + k];
        }
    pl += __shfl_xor(pl, 16, 64); pl += __shfl_xor(pl, 32, 64);
    pr += __shfl_xor(pr, 16, 64); pr += __shfl_xor(pr, 32, 64);
    if (q == 0) { lv[row] = pl; rv[row] = pr; }

    short8 ah[2], al[2];
    #pragma unroll
    for (int ks = 0; ks < 2; ++ks)
        #pragma unroll
        for (int j = 0; j < 8; ++j) {
            float f = xs[ks * 8 + j];
            unsigned hb = f2bf_rne(f);
            float res = f - bf2f(hb);
            ah[ks][j] = (short)hb;
            al[ks][j] = (short)f2bf_rne(res);
        }

    short8 bfr[4][2];
    #pragma unroll
    for (int nt = 0; nt < 4; ++nt)
        #pragma unroll
        for (int ks = 0; ks < 2; ++ks) {
            const float* wp = &Wcst[(nt * 16 + m) * 68 + ks * 32 + q * 8];
            float4 w0 = *(const float4*)wp;
            float4 w1 = *(const float4*)(wp + 4);
            short8 bf;
            bf[0] = (short)f2bf_rne(w0.x); bf[1] = (short)f2bf_rne(w0.y);
            bf[2] = (short)f2bf_rne(w0.z); bf[3] = (short)f2bf_rne(w0.w);
            bf[4] = (short)f2bf_rne(w1.x); bf[5] = (short)f2bf_rne(w1.y);
            bf[6] = (short)f2bf_rne(w1.z); bf[7] = (short)f2bf_rne(w1.w);
            bfr[nt][ks] = bf;
        }

    floatx4 acc[4] = {{0,0,0,0},{0,0,0,0},{0,0,0,0},{0,0,0,0}};
    #pragma unroll
    for (int ks = 0; ks < 2; ++ks)
        #pragma unroll
        for (int nt = 0; nt < 4; ++nt) {
            acc[nt] = __builtin_amdgcn_mfma_f32_16x16x32_bf16(ah[ks], bfr[nt][ks], acc[nt], 0, 0, 0);
            acc[nt] = __builtin_amdgcn_mfma_f32_16x16x32_bf16(al[ks], bfr[nt][ks], acc[nt], 0, 0, 0);
        }

    __syncthreads();
    #pragma unroll
    for (int nt = 0; nt < 4; ++nt)
        #pragma unroll
        for (int rg = 0; rg < 4; ++rg)
            GsT[(nt * 16 + m) * 68 + w * 16 + q * 4 + rg] = acc[nt][rg];
    __syncthreads();
    unsigned* Gu = (unsigned*)Gt;
    #pragma unroll
    for (int it2 = 0; it2 < 8; ++it2) {
        int c2 = (t >> 5) + it2 * 8;
        int np = t & 31;
        unsigned lo = f2bf_rne(GsT[c2 * 68 + 2 * np]);
        unsigned hi = f2bf_rne(GsT[c2 * 68 + 2 * np + 1]);
        Gu[(((((size_t)(b * 64 + c2)) << 12) + n0) >> 1) + np] = lo | (hi << 16);
    }
}

// ---- attn v8: block = (i-tile 64, b), 1024 thr = 16 INDEPENDENT waves
// wave = (isub: 16 i-rows, jq: 1024-j quarter). Zero barriers/LDS in K-loop.
// Register budget deliberately small (R7 spilled at ~160 live VGPRs):
// acc 20 + A-prefetch 16 + inline G/rv + temps ~= 80 live.
__global__ __launch_bounds__(1024, 4)
void attn_kernel(const float* __restrict__ A,
                 const unsigned short* __restrict__ Gt,
                 const float* __restrict__ lv,
                 const float* __restrict__ rv,
                 float* __restrict__ out) {
    __shared__ __align__(16) float red[2][64][68];      // 34816 B (epilogue only)
    const int bx = blockIdx.x;
    const int i0 = (bx & 63) * 64;
    const int b  = bx >> 6;
    const int t = threadIdx.x;
    const int wave = t >> 6, lane = t & 63;
    const int isub = wave & 3, jq = wave >> 2;
    const int m = lane & 15, q = lane >> 4;

    const int rg0 = i0 + isub * 16 + m;                  // this lane's E row
    const float li = lv[b * NN + rg0] * 1.44269504f;     // fold log2e (leaky commutes)

    const float* ap = A + (size_t)rg0 * NN + jq * 1024 + q * 8;
    const unsigned short* gp = Gt + (((size_t)(b * 64 + m)) << 12) + jq * 1024 + q * 8;
    const float* rp = rv + b * NN + jq * 1024 + q * 8;

    floatx4 acc0 = {0,0,0,0}, acc1 = {0,0,0,0}, acc2 = {0,0,0,0},
            acc3 = {0,0,0,0}, accd = {0,0,0,0};
    short8 ones;
    #pragma unroll
    for (int e = 0; e < 8; ++e) ones[e] = (short)0x3F80; // bf16 1.0

    auto genE = [&](float4 a0, float4 a1, float4 r0, float4 r1) -> short8 {
        const float aa[8] = {a0.x, a0.y, a0.z, a0.w, a1.x, a1.y, a1.z, a1.w};
        const float rr[8] = {r0.x, r0.y, r0.z, r0.w, r1.x, r1.y, r1.z, r1.w};
        unsigned ew[4];
        #pragma unroll
        for (int e2 = 0; e2 < 4; ++e2) {
            float s0 = li * rr[2 * e2], s1 = li * rr[2 * e2 + 1];
            s0 = fmaxf(s0, 0.01f * s0);                  // leaky_relu slope .01
            s1 = fmaxf(s1, 0.01f * s1);
            float e0 = exp2f(s0) * aa[2 * e2];
            float e1 = exp2f(s1) * aa[2 * e2 + 1];
            ew[e2] = __builtin_amdgcn_perm(__float_as_uint(e1) + 0x8000u,
                                           __float_as_uint(e0) + 0x8000u, 0x07060302u);
        }
        union { uint4 u; short8 s; } pk;
        pk.u.x = ew[0]; pk.u.y = ew[1]; pk.u.z = ew[2]; pk.u.w = ew[3];
        return pk.s;
    };

    // A prefetched 2 chunks ahead; G/rv loaded inline (L1/L2-resident).
    float4 ax0 = *(const float4*)(ap);
    float4 ax1 = *(const float4*)(ap + 4);
    float4 bx0 = *(const float4*)(ap + 32);
    float4 bx1 = *(const float4*)(ap + 36);

    for (int jj = 0; jj < 1024; jj += 64) {
        {   // chunk jj
            float4 r0 = *(const float4*)(rp + jj);
            float4 r1 = *(const float4*)(rp + jj + 4);
            short8 e = genE(ax0, ax1, r0, r1);
            const int jn = (jj + 64 < 1024) ? jj + 64 : jj;    // clamp tail
            ax0 = *(const float4*)(ap + jn);
            ax1 = *(const float4*)(ap + jn + 4);
            short8 g0 = *(const short8*)(gp + jj);
            short8 g1 = *(const short8*)(gp + jj + (16 << 12));
            short8 g2 = *(const short8*)(gp + jj + (32 << 12));
            short8 g3 = *(const short8*)(gp + jj + (48 << 12));
            acc0 = __builtin_amdgcn_mfma_f32_16x16x32_bf16(e, g0, acc0, 0, 0, 0);
            acc1 = __builtin_amdgcn_mfma_f32_16x16x32_bf16(e, g1, acc1, 0, 0, 0);
            acc2 = __builtin_amdgcn_mfma_f32_16x16x32_bf16(e, g2, acc2, 0, 0, 0);
            acc3 = __builtin_amdgcn_mfma_f32_16x16x32_bf16(e, g3, acc3, 0, 0, 0);
            accd = __builtin_amdgcn_mfma_f32_16x16x32_bf16(e, ones, accd, 0, 0, 0);
        }
        {   // chunk jj+32
            float4 r0 = *(const float4*)(rp + jj + 32);
            float4 r1 = *(const float4*)(rp + jj + 36);
            short8 e = genE(bx0, bx1, r0, r1);
            const int jn = (jj + 96 < 1024) ? jj + 96 : jj + 32;
            bx0 = *(const float4*)(ap + jn);
            bx1 = *(const float4*)(ap + jn + 4);
            short8 g0 = *(const short8*)(gp + jj + 32);
            short8 g1 = *(const short8*)(gp + jj + 32 + (16 << 12));
            short8 g2 = *(const short8*)(gp + jj + 32 + (32 << 12));
            short8 g3 = *(const short8*)(gp + jj + 32 + (48 << 12));
            acc0 = __builtin_amdgcn_mfma_f32_16x16x32_bf16(e, g0, acc0, 0, 0, 0);
            acc1 = __builtin_amdgcn_mfma_f32_16x16x32_bf16(e, g1, acc1, 0, 0, 0);
            acc2 = __builtin_amdgcn_mfma_f32_16x16x32_bf16(e, g2, acc2, 0, 0, 0);
            acc3 = __builtin_amdgcn_mfma_f32_16x16x32_bf16(e, g3, acc3, 0, 0, 0);
            accd = __builtin_amdgcn_mfma_f32_16x16x32_bf16(e, ones, accd, 0, 0, 0);
        }
    }

    // ---- epilogue: 2 passes x 2 jq-groups through LDS; accumulate in regs ----
    const int il = t >> 4, c4 = t & 15;
    float4 osum = {0.f, 0.f, 0.f, 0.f};
    float dsum = 0.f;
    #pragma unroll
    for (int p = 0; p < 2; ++p) {
        if ((jq >> 1) == p) {
            float (*rp_)[68] = red[jq & 1];
            #pragma unroll
            for (int rg = 0; rg < 4; ++rg) {
                const int r = isub * 16 + q * 4 + rg;
                rp_[r][m]      = acc0[rg];
                rp_[r][16 + m] = acc1[rg];
                rp_[r][32 + m] = acc2[rg];
                rp_[r][48 + m] = acc3[rg];
                if (m == 0) rp_[r][64] = accd[rg];
            }
        }
        __syncthreads();
        {
            float4 v0 = *(const float4*)&red[0][il][c4 * 4];
            float4 v1 = *(const float4*)&red[1][il][c4 * 4];
            osum.x += v0.x + v1.x; osum.y += v0.y + v1.y;
            osum.z += v0.z + v1.z; osum.w += v0.w + v1.w;
            dsum += red[0][il][64] + red[1][il][64];
        }
        __syncthreads();
    }

    // ---- diag correction (fp32): replace a_ii*e_ii by 1*e_ii (R7-verified) ----
    const int gi = i0 + il;
    {
        float lir = lv[b * NN + gi] * 1.44269504f;
        float rvi = rv[b * NN + gi];
        float s = lir * rvi;
        s = fmaxf(s, 0.01f * s);
        float eii = exp2f(s);
        float ad = A[(size_t)gi * NN + gi];
        float dc = (1.0f - ad) * eii;
        dsum += dc;
        osum.x += dc * bf2f(Gt[(((size_t)(b * 64 + c4 * 4 + 0)) << 12) + gi]);
        osum.y += dc * bf2f(Gt[(((size_t)(b * 64 + c4 * 4 + 1)) << 12) + gi]);
        osum.z += dc * bf2f(Gt[(((size_t)(b * 64 + c4 * 4 + 2)) << 12) + gi]);
        osum.w += dc * bf2f(Gt[(((size_t)(b * 64 + c4 * 4 + 3)) << 12) + gi]);
    }

    const float rinv = 1.0f / dsum;
    float4 o;
    o.x = osum.x * rinv; o.y = osum.y * rinv;
    o.z = osum.z * rinv; o.w = osum.w * rinv;
    *(float4*)(out + (((size_t)(b * NN + gi)) << 6) + c4 * 4) = o;
}

extern "C" void kernel_launch(void* const* d_in, const int* in_sizes, int n_in,
                              void* d_out, int out_size, void* d_ws, size_t ws_size,
                              hipStream_t stream) {
    const float* X     = (const float*)d_in[0];
    const float* A     = (const float*)d_in[1];
    const float* W1    = (const float*)d_in[2];
    const float* W2    = (const float*)d_in[3];
    const float* alpha = (const float*)d_in[4];
    float* out = (float*)d_out;

    char* ws = (char*)d_ws;
    unsigned short* Gt = (unsigned short*)(ws);            // 2 MiB
    float* lvp = (float*)(ws + 2097152);                   // 64 KiB
    float* rvp = (float*)(ws + 2097152 + 65536);           // 64 KiB

    prep_kernel<<<256, 256, 0, stream>>>(X, W1, W2, alpha, Gt, lvp, rvp);
    attn_kernel<<<256, 1024, 0, stream>>>(A, Gt, lvp, rvp, out);
}